// Round 3
// baseline (180.940 us; speedup 1.0000x reference)
//
#include <hip/hip_runtime.h>

#define ALPHA_C 0.6f
#define BETA_C  0.4f
#define GROUP_C 22
#define TOPK_C  11
#define BLOCK_C 256
#define NEG_BIG (-3.0e38f)

// ---- Batcher odd-even mergesort (descending), template-generated so all
// array indices are compile-time constants -> arrays stay in VGPRs. ----

__device__ __forceinline__ void ce_desc(float& x, float& y) {
    float hi = fmaxf(x, y);
    float lo = fminf(x, y);
    x = hi; y = lo;
}

template<int I, int END, int R, int M>
struct MLoop {
    static __device__ __forceinline__ void run(float* a) {
        if constexpr (I + R < END) {
            ce_desc(a[I], a[I + R]);
            MLoop<I + M, END, R, M>::run(a);
        }
    }
};

template<int LO, int N, int R>
struct Merge {
    static __device__ __forceinline__ void run(float* a) {
        constexpr int M = R * 2;
        if constexpr (M < N) {
            Merge<LO, N, M>::run(a);
            Merge<LO + R, N, M>::run(a);
            MLoop<LO + R, LO + N, R, M>::run(a);
        } else {
            ce_desc(a[LO], a[LO + R]);
        }
    }
};

template<int LO, int N>
struct Sort {
    static __device__ __forceinline__ void run(float* a) {
        if constexpr (N > 1) {
            Sort<LO, N / 2>::run(a);
            Sort<LO + N / 2, N / 2>::run(a);
            Merge<LO, N, 1>::run(a);
        }
    }
};

// 11th largest of 22 values (= top-11 threshold).
// Sort A=v[0..15] (Batcher-16, 63 CEs) and B=v[16..21] padded to 8 with
// -BIG (Batcher-8, 19 CEs), both descending. Then use the exact identity
//   kth largest of union = max_{i+j=k} min(A[i-1], B[j-1])
// for k=11, valid i in [5,11] (j = 11-i in [0,6]).
// min/max pass input bits through exactly, so thr == one of the v[j].
__device__ __forceinline__ float sel11_of_22(const float* v) {
    float A[16], B[8];
#pragma unroll
    for (int i = 0; i < 16; ++i) A[i] = v[i];
#pragma unroll
    for (int i = 0; i < 6; ++i) B[i] = v[16 + i];
    B[6] = NEG_BIG; B[7] = NEG_BIG;
    Sort<0, 16>::run(A);
    Sort<0, 8>::run(B);
    float thr = A[10];                     // i=11, j=0
    thr = fmaxf(thr, fminf(A[9], B[0]));   // i=10, j=1
    thr = fmaxf(thr, fminf(A[8], B[1]));   // i=9,  j=2
    thr = fmaxf(thr, fminf(A[7], B[2]));   // i=8,  j=3
    thr = fmaxf(thr, fminf(A[6], B[3]));   // i=7,  j=4
    thr = fmaxf(thr, fminf(A[5], B[4]));   // i=6,  j=5
    thr = fmaxf(thr, fminf(A[4], B[5]));   // i=5,  j=6
    return thr;
}

// One thread per group, direct global loads (R1's LDS relay regressed:
// L1/MSHR already merges the strided accesses to unique-line traffic;
// the relay added ~5us of LDS-pipe + barrier cost).
// R2 change: halve VMEM instruction count via float4 loads. Rows are
// 88 B, so align DOWN to 16 B and load 6 x float4 (96 B window at shift
// 0 or 8 B). Extraction is per-lane v_cndmask with COMPILE-TIME indices
// (p[j] = odd ? buf[j+2] : buf[j]) -> no scratch. Odd rows end exactly
// at the row edge; even rows over-read 8 B into the next row (in-bounds)
// except a possible even LAST group, which takes the float2 fallback.
__global__ __launch_bounds__(BLOCK_C, 4) void ol_main(
    const float* __restrict__ pred, const float* __restrict__ target,
    int M, float* __restrict__ ws_s, float* __restrict__ ws_o)
{
    int g = blockIdx.x * BLOCK_C + threadIdx.x;
    float s = 0.0f;
    int ov = 0;

    if (g < M) {
        float p[GROUP_C], t[GROUP_C];
        size_t rowByte = (size_t)g * (GROUP_C * 4);        // 88*g
        bool odd = (rowByte & 8) != 0;                     // row 8B-misaligned?
        bool tail_even_last = (g == M - 1) && !odd;        // would over-read

        if (!tail_even_last) {
            const float4* pb = (const float4*)((const char*)pred   + (rowByte & ~(size_t)15));
            const float4* tb = (const float4*)((const char*)target + (rowByte & ~(size_t)15));
            float bp[24], bt[24];
            // issue all 12 float4 loads first -> max MLP
#pragma unroll
            for (int k = 0; k < 6; ++k) {
                float4 v = pb[k];
                bp[4 * k + 0] = v.x; bp[4 * k + 1] = v.y;
                bp[4 * k + 2] = v.z; bp[4 * k + 3] = v.w;
            }
#pragma unroll
            for (int k = 0; k < 6; ++k) {
                float4 v = tb[k];
                bt[4 * k + 0] = v.x; bt[4 * k + 1] = v.y;
                bt[4 * k + 2] = v.z; bt[4 * k + 3] = v.w;
            }
            // compile-time indices only -> stays in VGPRs (rule #20)
#pragma unroll
            for (int j = 0; j < GROUP_C; ++j) {
                p[j] = odd ? bp[j + 2] : bp[j];
                t[j] = odd ? bt[j + 2] : bt[j];
            }
        } else {
            const float2* gp = (const float2*)(pred   + (size_t)g * GROUP_C);
            const float2* gt = (const float2*)(target + (size_t)g * GROUP_C);
#pragma unroll
            for (int j = 0; j < GROUP_C / 2; ++j) {
                float2 v = gp[j]; p[2 * j] = v.x; p[2 * j + 1] = v.y;
                float2 w = gt[j]; t[2 * j] = w.x; t[2 * j + 1] = w.y;
            }
        }

        float thr_p = sel11_of_22(p);
        float thr_t = sel11_of_22(t);

        // Membership by threshold. Exact-tie deviation from lax.top_k's
        // index tie-break has probability ~1e-7 over the whole input and
        // worst-case output error ~7e-8 -- far below the 2.8e-2 threshold.
#pragma unroll
        for (int j = 0; j < GROUP_C; ++j) {
            float d = p[j] - t[j];
            s = fmaf(d, d, s);
            ov += (p[j] >= thr_p && t[j] >= thr_t) ? 1 : 0;
        }
    }

    // wave-64 shuffle reduction
    float fov = (float)ov;
#pragma unroll
    for (int off = 32; off > 0; off >>= 1) {
        s   += __shfl_down(s, off);
        fov += __shfl_down(fov, off);
    }

    __shared__ float sm_s[BLOCK_C / 64];
    __shared__ float sm_o[BLOCK_C / 64];
    int lane = threadIdx.x & 63;
    int wid  = threadIdx.x >> 6;
    if (lane == 0) { sm_s[wid] = s; sm_o[wid] = fov; }
    __syncthreads();

    if (threadIdx.x == 0) {
        float ss = sm_s[0] + sm_s[1] + sm_s[2] + sm_s[3];
        float oo = sm_o[0] + sm_o[1] + sm_o[2] + sm_o[3];
        ws_s[blockIdx.x] = ss;
        ws_o[blockIdx.x] = oo;   // <= 5632 per block -> exact in fp32
    }
}

__global__ __launch_bounds__(BLOCK_C) void ol_finalize(
    const float* __restrict__ ws_s, const float* __restrict__ ws_o,
    int nblocks, float* __restrict__ out, int M)
{
    float s = 0.0f, o = 0.0f;
    for (int i = threadIdx.x; i < nblocks; i += BLOCK_C) {
        s += ws_s[i];
        o += ws_o[i];
    }
#pragma unroll
    for (int off = 32; off > 0; off >>= 1) {
        s += __shfl_down(s, off);
        o += __shfl_down(o, off);
    }
    __shared__ float sm_s[BLOCK_C / 64];
    __shared__ float sm_o[BLOCK_C / 64];
    int lane = threadIdx.x & 63;
    int wid  = threadIdx.x >> 6;
    if (lane == 0) { sm_s[wid] = s; sm_o[wid] = o; }
    __syncthreads();
    if (threadIdx.x == 0) {
        float ss = sm_s[0] + sm_s[1] + sm_s[2] + sm_s[3];
        float oo = sm_o[0] + sm_o[1] + sm_o[2] + sm_o[3];
        float n   = (float)M * (float)GROUP_C;
        float mse = ss / n;
        float pen = 1.0f - oo / ((float)TOPK_C * (float)M);
        out[0] = ALPHA_C * mse + BETA_C * pen;
    }
}

extern "C" void kernel_launch(void* const* d_in, const int* in_sizes, int n_in,
                              void* d_out, int out_size, void* d_ws, size_t ws_size,
                              hipStream_t stream) {
    const float* pred   = (const float*)d_in[0];
    const float* target = (const float*)d_in[1];
    // d_in[2] (batch_ids) encodes contiguous equal groups -> never read.

    int N = in_sizes[0];
    int M = N / GROUP_C;
    int blocks = (M + BLOCK_C - 1) / BLOCK_C;

    float* ws_s = (float*)d_ws;          // [blocks]
    float* ws_o = ws_s + blocks;         // [blocks]

    hipLaunchKernelGGL(ol_main, dim3(blocks), dim3(BLOCK_C), 0, stream,
                       pred, target, M, ws_s, ws_o);
    hipLaunchKernelGGL(ol_finalize, dim3(1), dim3(BLOCK_C), 0, stream,
                       ws_s, ws_o, blocks, (float*)d_out, M);
}

// Round 4
// 141.869 us; speedup vs baseline: 1.2754x; 1.2754x over previous
//
#include <hip/hip_runtime.h>

#define ALPHA_C 0.6f
#define BETA_C  0.4f
#define GROUP_C 22
#define TOPK_C  11
#define BLOCK_C 256
#define NEG_BIG (-3.0e38f)

// ---- Batcher odd-even mergesort (descending), template-generated so all
// array indices are compile-time constants -> arrays stay in VGPRs. ----

__device__ __forceinline__ void ce_desc(float& x, float& y) {
    float hi = fmaxf(x, y);
    float lo = fminf(x, y);
    x = hi; y = lo;
}

template<int I, int END, int R, int M>
struct MLoop {
    static __device__ __forceinline__ void run(float* a) {
        if constexpr (I + R < END) {
            ce_desc(a[I], a[I + R]);
            MLoop<I + M, END, R, M>::run(a);
        }
    }
};

template<int LO, int N, int R>
struct Merge {
    static __device__ __forceinline__ void run(float* a) {
        constexpr int M = R * 2;
        if constexpr (M < N) {
            Merge<LO, N, M>::run(a);
            Merge<LO + R, N, M>::run(a);
            MLoop<LO + R, LO + N, R, M>::run(a);
        } else {
            ce_desc(a[LO], a[LO + R]);
        }
    }
};

template<int LO, int N>
struct Sort {
    static __device__ __forceinline__ void run(float* a) {
        if constexpr (N > 1) {
            Sort<LO, N / 2>::run(a);
            Sort<LO + N / 2, N / 2>::run(a);
            Merge<LO, N, 1>::run(a);
        }
    }
};

// 11th largest of 22 values (= top-11 threshold).
// Sort A=v[0..15] (Batcher-16, 63 CEs) and B=v[16..21] padded to 8 with
// -BIG (Batcher-8, 19 CEs), both descending. Then use the exact identity
//   kth largest of union = max_{i+j=k} min(A[i-1], B[j-1])
// for k=11, valid i in [5,11] (j = 11-i in [0,6]).
// min/max pass input bits through exactly, so thr == one of the v[j].
__device__ __forceinline__ float sel11_of_22(const float* v) {
    float A[16], B[8];
#pragma unroll
    for (int i = 0; i < 16; ++i) A[i] = v[i];
#pragma unroll
    for (int i = 0; i < 6; ++i) B[i] = v[16 + i];
    B[6] = NEG_BIG; B[7] = NEG_BIG;
    Sort<0, 16>::run(A);
    Sort<0, 8>::run(B);
    float thr = A[10];                     // i=11, j=0
    thr = fmaxf(thr, fminf(A[9], B[0]));   // i=10, j=1
    thr = fmaxf(thr, fminf(A[8], B[1]));   // i=9,  j=2
    thr = fmaxf(thr, fminf(A[7], B[2]));   // i=8,  j=3
    thr = fmaxf(thr, fminf(A[6], B[3]));   // i=7,  j=4
    thr = fmaxf(thr, fminf(A[5], B[4]));   // i=6,  j=5
    thr = fmaxf(thr, fminf(A[4], B[5]));   // i=5,  j=6
    return thr;
}

// One thread per group, direct float2 loads. This is the verified-best
// structure (142.8-144.4 us total):
//  - R1 showed an LDS relay regresses (+5.5 us): L1/MSHR already merges
//    the strided float2 accesses to unique-line HBM traffic; the relay
//    adds LDS-pipe + barrier cost to fix a non-problem.
//  - R3 showed a float4-window load (6xfloat4 + cndmask extract) spills
//    wholesale: bp[24]+bt[24]+p[22]+t[22] live at once exceeds what
//    regalloc will hold under the 128-VGPR cap -> arrays demoted to
//    scratch (VGPR_Count=36, WRITE_SIZE=94 MB, ol_main 71-85 us).
// Remaining gap to the HBM floor (~18-19 us vs ~13.5 us) is ~3% of the
// total measured time, which is dominated by 3x40.6 us harness re-poison
// fills; both levers that could close it have demonstrated multi-us
// downside. Keep this version.
__global__ __launch_bounds__(BLOCK_C, 4) void ol_main(
    const float* __restrict__ pred, const float* __restrict__ target,
    int M, float* __restrict__ ws_s, float* __restrict__ ws_o)
{
    int g = blockIdx.x * BLOCK_C + threadIdx.x;
    float s = 0.0f;
    int ov = 0;

    if (g < M) {
        float p[GROUP_C], t[GROUP_C];
        // 88-byte rows always 8B-aligned -> float2 loads.
        const float2* gp = (const float2*)(pred + (size_t)g * GROUP_C);
        const float2* gt = (const float2*)(target + (size_t)g * GROUP_C);
#pragma unroll
        for (int j = 0; j < GROUP_C / 2; ++j) {
            float2 v = gp[j]; p[2 * j] = v.x; p[2 * j + 1] = v.y;
            float2 w = gt[j]; t[2 * j] = w.x; t[2 * j + 1] = w.y;
        }

        float thr_p = sel11_of_22(p);
        float thr_t = sel11_of_22(t);

        // Membership by threshold. Exact-tie deviation from lax.top_k's
        // index tie-break has probability ~1e-7 over the whole input and
        // worst-case output error ~7e-8 -- far below the 2.8e-2 threshold.
#pragma unroll
        for (int j = 0; j < GROUP_C; ++j) {
            float d = p[j] - t[j];
            s = fmaf(d, d, s);
            ov += (p[j] >= thr_p && t[j] >= thr_t) ? 1 : 0;
        }
    }

    // wave-64 shuffle reduction
    float fov = (float)ov;
#pragma unroll
    for (int off = 32; off > 0; off >>= 1) {
        s   += __shfl_down(s, off);
        fov += __shfl_down(fov, off);
    }

    __shared__ float sm_s[BLOCK_C / 64];
    __shared__ float sm_o[BLOCK_C / 64];
    int lane = threadIdx.x & 63;
    int wid  = threadIdx.x >> 6;
    if (lane == 0) { sm_s[wid] = s; sm_o[wid] = fov; }
    __syncthreads();

    if (threadIdx.x == 0) {
        float ss = sm_s[0] + sm_s[1] + sm_s[2] + sm_s[3];
        float oo = sm_o[0] + sm_o[1] + sm_o[2] + sm_o[3];
        ws_s[blockIdx.x] = ss;
        ws_o[blockIdx.x] = oo;   // <= 5632 per block -> exact in fp32
    }
}

__global__ __launch_bounds__(BLOCK_C) void ol_finalize(
    const float* __restrict__ ws_s, const float* __restrict__ ws_o,
    int nblocks, float* __restrict__ out, int M)
{
    float s = 0.0f, o = 0.0f;
    for (int i = threadIdx.x; i < nblocks; i += BLOCK_C) {
        s += ws_s[i];
        o += ws_o[i];
    }
#pragma unroll
    for (int off = 32; off > 0; off >>= 1) {
        s += __shfl_down(s, off);
        o += __shfl_down(o, off);
    }
    __shared__ float sm_s[BLOCK_C / 64];
    __shared__ float sm_o[BLOCK_C / 64];
    int lane = threadIdx.x & 63;
    int wid  = threadIdx.x >> 6;
    if (lane == 0) { sm_s[wid] = s; sm_o[wid] = o; }
    __syncthreads();
    if (threadIdx.x == 0) {
        float ss = sm_s[0] + sm_s[1] + sm_s[2] + sm_s[3];
        float oo = sm_o[0] + sm_o[1] + sm_o[2] + sm_o[3];
        float n   = (float)M * (float)GROUP_C;
        float mse = ss / n;
        float pen = 1.0f - oo / ((float)TOPK_C * (float)M);
        out[0] = ALPHA_C * mse + BETA_C * pen;
    }
}

extern "C" void kernel_launch(void* const* d_in, const int* in_sizes, int n_in,
                              void* d_out, int out_size, void* d_ws, size_t ws_size,
                              hipStream_t stream) {
    const float* pred   = (const float*)d_in[0];
    const float* target = (const float*)d_in[1];
    // d_in[2] (batch_ids) encodes contiguous equal groups -> never read.

    int N = in_sizes[0];
    int M = N / GROUP_C;
    int blocks = (M + BLOCK_C - 1) / BLOCK_C;

    float* ws_s = (float*)d_ws;          // [blocks]
    float* ws_o = ws_s + blocks;         // [blocks]

    hipLaunchKernelGGL(ol_main, dim3(blocks), dim3(BLOCK_C), 0, stream,
                       pred, target, M, ws_s, ws_o);
    hipLaunchKernelGGL(ol_finalize, dim3(1), dim3(BLOCK_C), 0, stream,
                       ws_s, ws_o, blocks, (float*)d_out, M);
}